// Round 14
// baseline (323.959 us; speedup 1.0000x reference)
//
#include <hip/hip_runtime.h>
#include <hip/hip_bf16.h>

typedef short bf16x8 __attribute__((ext_vector_type(8)));
typedef float f32x4 __attribute__((ext_vector_type(4)));

#define K_DIM 4096
#define N_DIM 16384
#define M_DIM 2048
#define STRIPE 16384                       // bytes per (tile128, kstep64) stripe in ws
#define TSTRIDE (64 * STRIPE)              // bytes per 128-row tile (1 MiB)
#define WSB_BYTES ((size_t)N_DIM * K_DIM * 2)   // 134217728
#define WSA_BYTES ((size_t)M_DIM * K_DIM * 2)   // 16777216

__device__ __forceinline__ unsigned f2bf(float f) {
    unsigned u = __builtin_bit_cast(unsigned, f);
    u += 0x7FFFu + ((u >> 16) & 1u);
    return u >> 16;   // RNE, inputs finite
}

// NVFP4 e2m1 nibble -> f32 (branchless), times scale
__device__ __forceinline__ float dec4(unsigned c, float s) {
    unsigned mag = c & 7u;
    unsigned u = (mag >= 2u) ? ((((mag >> 1) + 126u) << 23) | ((mag & 1u) << 22))
                             : (mag == 1u ? 0x3F000000u : 0u);
    u |= (c & 8u) << 28;   // sign
    return __builtin_bit_cast(float, u) * s;
}

// fast tanh-GELU (r12-verified): tanh(z) = (1-t)*rcp(1+t), t = 2^(-2*log2(e)*z).
__device__ __forceinline__ float fexp2(float x) {
    float r; asm("v_exp_f32 %0, %1" : "=v"(r) : "v"(x)); return r;
}
__device__ __forceinline__ float gelu_tanh(float v) {
    float c = v + 0.044715f * v * v * v;
    float x = fminf(-2.3022084f * c, 80.0f);   // -2*log2(e)*0.7978845608 * c
    float t = fexp2(x);
    float th = (1.0f - t) * __builtin_amdgcn_rcpf(1.0f + t);
    return 0.5f * v * (1.0f + th);
}

// ---------------- Pass 1a: dequant W -> bf16, tiled + pre-swizzled (verified) -----------
__global__ __launch_bounds__(256) void dequant_w(const int* __restrict__ wp,
                                                 const float* __restrict__ wsc,
                                                 unsigned char* __restrict__ dst) {
    int t = blockIdx.x * 256 + threadIdx.x;
    int n = t >> 9;
    int ck = t & 511;
    int kstep = ck >> 3, s = ck & 7;
    int nt = n >> 7, r = n & 127;

    const int4 p4 = *reinterpret_cast<const int4*>(wp + (size_t)n * (K_DIM / 2) + kstep * 32 + s * 4);
    float scale = wsc[(size_t)n * (K_DIM / 32) + kstep * 2 + (s >> 2)];

    const int pv[4] = {p4.x, p4.y, p4.z, p4.w};
    unsigned o[8];
    #pragma unroll
    for (int j = 0; j < 4; ++j) {
        unsigned b = (unsigned)pv[j] & 255u;
        o[2 * j]     = f2bf(dec4(b & 15u, scale));
        o[2 * j + 1] = f2bf(dec4((b >> 4) & 15u, scale));
    }
    uint4 v;
    v.x = o[0] | (o[1] << 16);
    v.y = o[2] | (o[3] << 16);
    v.z = o[4] | (o[5] << 16);
    v.w = o[6] | (o[7] << 16);

    size_t off = (size_t)(nt * 64 + kstep) * STRIPE
               + (size_t)r * 128 + (size_t)((s ^ (r & 7)) << 4);
    *reinterpret_cast<uint4*>(dst + off) = v;
}

// ---------------- Pass 1b: x f32 -> bf16, tiled + pre-swizzled (verified) ---------------
__global__ __launch_bounds__(256) void conv_x(const float* __restrict__ x,
                                              unsigned char* __restrict__ dst) {
    int t = blockIdx.x * 256 + threadIdx.x;
    int m = t >> 9;
    int ck = t & 511;
    int kstep = ck >> 3, s = ck & 7;
    int mt = m >> 7, r = m & 127;

    const float4* xp = reinterpret_cast<const float4*>(x + (size_t)m * K_DIM + kstep * 64 + s * 8);
    float4 a = xp[0], b = xp[1];
    uint4 v;
    v.x = f2bf(a.x) | (f2bf(a.y) << 16);
    v.y = f2bf(a.z) | (f2bf(a.w) << 16);
    v.z = f2bf(b.x) | (f2bf(b.y) << 16);
    v.w = f2bf(b.z) | (f2bf(b.w) << 16);

    size_t off = (size_t)(mt * 64 + kstep) * STRIPE
               + (size_t)r * 128 + (size_t)((s ^ (r & 7)) << 4);
    *reinterpret_cast<uint4*>(dst + off) = v;
}

// ---------------- Pass 2: 256^2 bf16 GEMM, 16 waves / 4-per-SIMD regime -----------------
// 1024 threads (16 waves, 4M x 4N), per-wave 64x64 = 4x4 frags of 16x16, BK=32.
// acc = 64 VGPR -> total <=128 VGPR -> 4 waves/SIMD (launch_bounds(1024,4) enforces).
// Ring-4 LDS slots (32 KiB each: A at s<<15, B at +16K), stage(t+3) during tile t,
// counted vmcnt(2) per tile (1 A-load + 1 B-load per thread per tile).
// Read/staging layouts = r3-verified zero-conflict formulas (thread-index generalized).
// Mechanism vs r13: 2x the waves/SIMD to hide the barrier+lgkm gaps (the measured
// 46% MFMA-idle); trades reg-prefetch (impossible at this VGPR budget) for TLP.

__global__ __launch_bounds__(1024, 4) void gemm_bf16_256(
    const unsigned char* __restrict__ wsA,
    const unsigned char* __restrict__ wsB,
    const float* __restrict__ bias,
    float* __restrict__ out)
{
    __shared__ unsigned char lds[131072];   // 4 ring slots x (A 16K + B 16K)

    // XCD-chunked bijective swizzle
    int id = blockIdx.x;
    int wg = (id & 7) * 64 + (id >> 3);
    int MT = wg & 7;        // 0..7
    int NT = wg >> 3;       // 0..63

    const int tid  = threadIdx.x;
    const int lane = tid & 63;
    const int w    = tid >> 6;   // 0..15
    const int wm   = w >> 2;     // 0..3
    const int wn   = w & 3;      // 0..3
    const int fr   = lane & 15;  // fragment row
    const int fg   = lane >> 4;  // K-quarter 0..3

    const unsigned char* gA = wsA + (size_t)(2 * MT) * TSTRIDE;
    const unsigned char* gB = wsB + (size_t)(2 * NT) * TSTRIDE;

    // ds_read byte addresses (r3 zero-conflict formulas; rows 0..255, 16 KiB region)
    int addrA[4];
    #pragma unroll
    for (int mi = 0; mi < 4; ++mi) {
        int row = wm * 64 + mi * 16 + fr;
        int L = row >> 1;
        addrA[mi] = L * 128 + (((((row & 1) << 2) | fg) ^ (L & 7)) << 4);
    }
    int addrB[4];
    #pragma unroll
    for (int ni = 0; ni < 4; ++ni) {
        int row = wn * 64 + ni * 16 + fr;
        int L = row >> 1;
        addrB[ni] = L * 128 + (((((row & 1) << 2) | fg) ^ (L & 7)) << 4);
    }

    // staging source offsets: thread covers 16-B LDS slot S = tid (1024 slots = 16 KiB)
    int offST[2];   // [kb]
    {
        int S = tid;
        int L = S >> 3;
        int p = S & 7;
        int hp = p ^ (L & 7);
        int row = 2 * L + (hp >> 2);
        int kq = hp & 3;
        #pragma unroll
        for (int kb = 0; kb < 2; ++kb)
            offST[kb] = (row >> 7) * TSTRIDE + (row & 127) * 128
                      + ((((kb << 2) | kq) ^ (row & 7)) << 4);
    }
    const int dstST = tid * 16;   // wave-uniform base + lane*16 within each wave

#define GLDS(SRC, DOFF) __builtin_amdgcn_global_load_lds(                          \
        (const __attribute__((address_space(1))) unsigned int*)(SRC),              \
        (__attribute__((address_space(3))) unsigned int*)(&lds[DOFF]), 16, 0, 0)

#define STAGE_A(KSOFF, KB, SLOT) GLDS(gA + (KSOFF) + offST[KB], ((SLOT) << 15) + dstST)
#define STAGE_B(KSOFF, KB, SLOT) GLDS(gB + (KSOFF) + offST[KB], ((SLOT) << 15) + 16384 + dstST)

    f32x4 acc[4][4];
    #pragma unroll
    for (int mi = 0; mi < 4; ++mi)
        #pragma unroll
        for (int ni = 0; ni < 4; ++ni)
            acc[mi][ni] = (f32x4){0.f, 0.f, 0.f, 0.f};

    // prologue: stage tiles 0,1,2 into slots 0,1,2 (6 loads); vmcnt(2) -> 0,1 done.
    STAGE_A(0, 0, 0);        STAGE_B(0, 0, 0);
    STAGE_A(0, 1, 1);        STAGE_B(0, 1, 1);
    STAGE_A(STRIPE, 0, 2);   STAGE_B(STRIPE, 0, 2);
    asm volatile("s_waitcnt vmcnt(2)" ::: "memory");
    __builtin_amdgcn_sched_barrier(0);
    __builtin_amdgcn_s_barrier();
    __builtin_amdgcn_sched_barrier(0);

// one K-tile: stage A(t+3); read 4 B + 4 A frags; stage B(t+3); 16 MFMA;
// counted vmcnt boundary (2 = steady, 0 = tail drain, -1 = last tile).
#define TILE_BODY(RSLOT, DO_STG, STKS, STKB, SSLOT, VMN) do {                      \
        const unsigned char* la = lds + ((RSLOT) << 15);                           \
        const unsigned char* lb = la + 16384;                                      \
        bf16x8 af[4], bf[4];                                                       \
        if (DO_STG) STAGE_A(STKS, STKB, SSLOT);                                    \
        _Pragma("unroll") for (int ni = 0; ni < 4; ++ni)                           \
            bf[ni] = *reinterpret_cast<const bf16x8*>(lb + addrB[ni]);             \
        _Pragma("unroll") for (int mi = 0; mi < 4; ++mi)                           \
            af[mi] = *reinterpret_cast<const bf16x8*>(la + addrA[mi]);             \
        if (DO_STG) STAGE_B(STKS, STKB, SSLOT);                                    \
        _Pragma("unroll") for (int mi = 0; mi < 4; ++mi)                           \
            _Pragma("unroll") for (int ni = 0; ni < 4; ++ni)                       \
                acc[mi][ni] = __builtin_amdgcn_mfma_f32_16x16x32_bf16(             \
                    af[mi], bf[ni], acc[mi][ni], 0, 0, 0);                         \
        if ((VMN) >= 0) {                                                          \
            if ((VMN) == 2)      asm volatile("s_waitcnt vmcnt(2)" ::: "memory");  \
            else                 asm volatile("s_waitcnt vmcnt(0)" ::: "memory");  \
            __builtin_amdgcn_sched_barrier(0);                                     \
            __builtin_amdgcn_s_barrier();                                          \
            __builtin_amdgcn_sched_barrier(0);                                     \
        }                                                                          \
    } while (0)

    // main loop: tiles t = 2tp, 2tp+1 for tp = 0..61; stage tile t+3; vmcnt(2) cadence.
    for (int tp = 0; tp < 62; ++tp) {
        const int scur = (tp & 1) << 1;              // slot of tile 2tp (0 or 2)
        const int ks1 = (tp + 1) * STRIPE;           // stage tile 2tp+3 (kb=1)
        const int ks2 = (tp + 2) * STRIPE;           // stage tile 2tp+4 (kb=0)
        TILE_BODY(scur,     1, ks1, 1, scur ^ 3, 2);
        TILE_BODY(scur ^ 1, 1, ks2, 0, scur,     2);
    }
    // tail: tiles 124..127 in slots 0..3; stage only 127; drain 2 -> 2 -> 0 -> none.
    TILE_BODY(0, 1, 63 * STRIPE, 1, 3, 2);
    TILE_BODY(1, 0, 0, 0, 0, 2);
    TILE_BODY(2, 0, 0, 0, 0, 0);
    TILE_BODY(3, 0, 0, 0, 0, -1);

    // epilogue: bias + fast tanh-GELU, f32 stores (16x16 C/D layout: col=lane&15,
    // row = (lane>>4)*4 + reg).
    const int bm0 = MT * 256, bn0 = NT * 256;
    #pragma unroll
    for (int mi = 0; mi < 4; ++mi) {
        int row = bm0 + wm * 64 + mi * 16 + fg * 4;
        #pragma unroll
        for (int ni = 0; ni < 4; ++ni) {
            int col = bn0 + wn * 64 + ni * 16 + fr;
            float bv = bias[col];
            float* op = out + (size_t)row * N_DIM + col;
            #pragma unroll
            for (int q = 0; q < 4; ++q) {
                float v = acc[mi][ni][q] + bv;
                op[(size_t)q * N_DIM] = gelu_tanh(v);
            }
        }
    }
#undef TILE_BODY
#undef STAGE_A
#undef STAGE_B
#undef GLDS
}

// ---------------- Fallback: round-1 fused kernel (used only if ws too small) ------------
__global__ __launch_bounds__(256, 2) void nvfp4_gemm(
    const float* __restrict__ x,
    const int*   __restrict__ wp,
    const float* __restrict__ wscale,
    const float* __restrict__ bias,
    float* __restrict__ out)
{
    __shared__ uint4  lsA[128 * 8];
    __shared__ uint4  lsB[128 * 8];
    __shared__ float2 lut[256];

    const int tid = threadIdx.x;
    {
        static const float dectab[16] = {0.f, 0.5f, 1.f, 1.5f, 2.f, 3.f, 4.f, 6.f,
                                         -0.f,-0.5f,-1.f,-1.5f,-2.f,-3.f,-4.f,-6.f};
        lut[tid] = make_float2(dectab[tid & 15], dectab[(tid >> 4) & 15]);
    }

    const int bn0 = blockIdx.x * 128;
    const int bm0 = blockIdx.y * 128;
    const int r = tid >> 1;
    const int h = tid & 1;

    const float4* xp = reinterpret_cast<const float4*>(x + (size_t)(bm0 + r) * K_DIM) + h * 8;
    const uint4*  bp = reinterpret_cast<const uint4*>(wp + (size_t)(bn0 + r) * (K_DIM / 2)) + h * 4;
    const float*  sp = wscale + (size_t)(bn0 + r) * (K_DIM / 32) + h;

    float4 ax[8];
    uint4  bx[4];
    float  scale;
    #pragma unroll
    for (int j = 0; j < 8; ++j) ax[j] = xp[j];
    #pragma unroll
    for (int q = 0; q < 4; ++q) bx[q] = bp[q];
    scale = sp[0];

    f32x4 acc[4][4];
    #pragma unroll
    for (int mi = 0; mi < 4; ++mi)
        #pragma unroll
        for (int ni = 0; ni < 4; ++ni)
            acc[mi][ni] = (f32x4){0.f, 0.f, 0.f, 0.f};

    const int lane = tid & 63;
    const int wid  = tid >> 6;
    const int wm0  = (wid >> 1) * 64;
    const int wn0  = (wid & 1) * 64;
    const int fr   = lane & 15;
    const int fg   = lane >> 4;

    __syncthreads();

    for (int kt = 0; kt < 64; ++kt) {
        #pragma unroll
        for (int j = 0; j < 4; ++j) {
            float4 f0 = ax[2 * j], f1 = ax[2 * j + 1];
            uint4 v;
            v.x = f2bf(f0.x) | (f2bf(f0.y) << 16);
            v.y = f2bf(f0.z) | (f2bf(f0.w) << 16);
            v.z = f2bf(f1.x) | (f2bf(f1.y) << 16);
            v.w = f2bf(f1.z) | (f2bf(f1.w) << 16);
            lsA[(r * 8 + h * 4 + j) ^ (r & 7)] = v;
        }
        #pragma unroll
        for (int q = 0; q < 4; ++q) {
            uint4 p = bx[q];
            float2 d0 = lut[p.x & 255];
            float2 d1 = lut[p.y & 255];
            float2 d2 = lut[p.z & 255];
            float2 d3 = lut[p.w & 255];
            uint4 v;
            v.x = f2bf(d0.x * scale) | (f2bf(d0.y * scale) << 16);
            v.y = f2bf(d1.x * scale) | (f2bf(d1.y * scale) << 16);
            v.z = f2bf(d2.x * scale) | (f2bf(d2.y * scale) << 16);
            v.w = f2bf(d3.x * scale) | (f2bf(d3.y * scale) << 16);
            lsB[(r * 8 + h * 4 + q) ^ (r & 7)] = v;
        }
        __syncthreads();

        if (kt + 1 < 64) {
            #pragma unroll
            for (int j = 0; j < 8; ++j) ax[j] = xp[(kt + 1) * 16 + j];
            #pragma unroll
            for (int q = 0; q < 4; ++q) bx[q] = bp[(kt + 1) * 8 + q];
            scale = sp[(kt + 1) * 2];
        }

        #pragma unroll
        for (int kk = 0; kk < 2; ++kk) {
            bf16x8 af[4], bfr[4];
            #pragma unroll
            for (int mi = 0; mi < 4; ++mi) {
                int row = wm0 + mi * 16 + fr;
                af[mi] = __builtin_bit_cast(bf16x8, lsA[(row * 8 + kk * 4 + fg) ^ (row & 7)]);
            }
            #pragma unroll
            for (int ni = 0; ni < 4; ++ni) {
                int row = wn0 + ni * 16 + fr;
                bfr[ni] = __builtin_bit_cast(bf16x8, lsB[(row * 8 + kk * 4 + fg) ^ (row & 7)]);
            }
            #pragma unroll
            for (int mi = 0; mi < 4; ++mi)
                #pragma unroll
                for (int ni = 0; ni < 4; ++ni)
                    acc[mi][ni] = __builtin_amdgcn_mfma_f32_16x16x32_bf16(
                        af[mi], bfr[ni], acc[mi][ni], 0, 0, 0);
        }
        __syncthreads();
    }

    #pragma unroll
    for (int mi = 0; mi < 4; ++mi) {
        int row = bm0 + wm0 + mi * 16 + fg * 4;
        #pragma unroll
        for (int ni = 0; ni < 4; ++ni) {
            int col = bn0 + wn0 + ni * 16 + fr;
            float bv = bias[col];
            float* op = out + (size_t)row * N_DIM + col;
            #pragma unroll
            for (int q = 0; q < 4; ++q) {
                float v = acc[mi][ni][q] + bv;
                op[(size_t)q * N_DIM] = gelu_tanh(v);
            }
        }
    }
}

extern "C" void kernel_launch(void* const* d_in, const int* in_sizes, int n_in,
                              void* d_out, int out_size, void* d_ws, size_t ws_size,
                              hipStream_t stream) {
    const float* x    = (const float*)d_in[0];
    const int*   wp   = (const int*)d_in[1];
    const float* wsc  = (const float*)d_in[2];
    const float* bias = (const float*)d_in[3];
    float*       out  = (float*)d_out;
    (void)in_sizes; (void)n_in; (void)out_size;

    if (ws_size >= WSB_BYTES + WSA_BYTES) {
        unsigned char* wsB = (unsigned char*)d_ws;
        unsigned char* wsA = wsB + WSB_BYTES;
        dequant_w<<<(N_DIM * (K_DIM / 8)) / 256, 256, 0, stream>>>(wp, wsc, wsB);
        conv_x<<<(M_DIM * (K_DIM / 8)) / 256, 256, 0, stream>>>(x, wsA);
        gemm_bf16_256<<<(M_DIM / 256) * (N_DIM / 256), 1024, 0, stream>>>(wsA, wsB, bias, out);
    } else {
        dim3 grid(N_DIM / 128, M_DIM / 128);
        nvfp4_gemm<<<grid, 256, 0, stream>>>(x, wp, wsc, bias, out);
    }
}

// Round 15
// 296.459 us; speedup vs baseline: 1.0928x; 1.0928x over previous
//
#include <hip/hip_runtime.h>
#include <hip/hip_bf16.h>

typedef short bf16x8 __attribute__((ext_vector_type(8)));
typedef float f32x4 __attribute__((ext_vector_type(4)));

#define K_DIM 4096
#define N_DIM 16384
#define M_DIM 2048
#define STRIPE 16384                       // bytes per (tile128, kstep64) stripe in ws
#define TSTRIDE (64 * STRIPE)              // bytes per 128-row tile (1 MiB)
#define WSB_BYTES ((size_t)N_DIM * K_DIM * 2)   // 134217728
#define WSA_BYTES ((size_t)M_DIM * K_DIM * 2)   // 16777216

__device__ __forceinline__ unsigned f2bf(float f) {
    unsigned u = __builtin_bit_cast(unsigned, f);
    u += 0x7FFFu + ((u >> 16) & 1u);
    return u >> 16;   // RNE, inputs finite
}

// NVFP4 e2m1 nibble -> f32 (branchless), times scale
__device__ __forceinline__ float dec4(unsigned c, float s) {
    unsigned mag = c & 7u;
    unsigned u = (mag >= 2u) ? ((((mag >> 1) + 126u) << 23) | ((mag & 1u) << 22))
                             : (mag == 1u ? 0x3F000000u : 0u);
    u |= (c & 8u) << 28;   // sign
    return __builtin_bit_cast(float, u) * s;
}

// fast tanh-GELU (r12-verified): tanh(z) = (1-t)*rcp(1+t), t = 2^(-2*log2(e)*z).
__device__ __forceinline__ float fexp2(float x) {
    float r; asm("v_exp_f32 %0, %1" : "=v"(r) : "v"(x)); return r;
}
__device__ __forceinline__ float gelu_tanh(float v) {
    float c = v + 0.044715f * v * v * v;
    float x = fminf(-2.3022084f * c, 80.0f);   // -2*log2(e)*0.7978845608 * c
    float t = fexp2(x);
    float th = (1.0f - t) * __builtin_amdgcn_rcpf(1.0f + t);
    return 0.5f * v * (1.0f + th);
}

// ---------------- Pass 1a: dequant W -> bf16, tiled + pre-swizzled (verified) -----------
__global__ __launch_bounds__(256) void dequant_w(const int* __restrict__ wp,
                                                 const float* __restrict__ wsc,
                                                 unsigned char* __restrict__ dst) {
    int t = blockIdx.x * 256 + threadIdx.x;
    int n = t >> 9;
    int ck = t & 511;
    int kstep = ck >> 3, s = ck & 7;
    int nt = n >> 7, r = n & 127;

    const int4 p4 = *reinterpret_cast<const int4*>(wp + (size_t)n * (K_DIM / 2) + kstep * 32 + s * 4);
    float scale = wsc[(size_t)n * (K_DIM / 32) + kstep * 2 + (s >> 2)];

    const int pv[4] = {p4.x, p4.y, p4.z, p4.w};
    unsigned o[8];
    #pragma unroll
    for (int j = 0; j < 4; ++j) {
        unsigned b = (unsigned)pv[j] & 255u;
        o[2 * j]     = f2bf(dec4(b & 15u, scale));
        o[2 * j + 1] = f2bf(dec4((b >> 4) & 15u, scale));
    }
    uint4 v;
    v.x = o[0] | (o[1] << 16);
    v.y = o[2] | (o[3] << 16);
    v.z = o[4] | (o[5] << 16);
    v.w = o[6] | (o[7] << 16);

    size_t off = (size_t)(nt * 64 + kstep) * STRIPE
               + (size_t)r * 128 + (size_t)((s ^ (r & 7)) << 4);
    *reinterpret_cast<uint4*>(dst + off) = v;
}

// ---------------- Pass 1b: x f32 -> bf16, tiled + pre-swizzled (verified) ---------------
__global__ __launch_bounds__(256) void conv_x(const float* __restrict__ x,
                                              unsigned char* __restrict__ dst) {
    int t = blockIdx.x * 256 + threadIdx.x;
    int m = t >> 9;
    int ck = t & 511;
    int kstep = ck >> 3, s = ck & 7;
    int mt = m >> 7, r = m & 127;

    const float4* xp = reinterpret_cast<const float4*>(x + (size_t)m * K_DIM + kstep * 64 + s * 8);
    float4 a = xp[0], b = xp[1];
    uint4 v;
    v.x = f2bf(a.x) | (f2bf(a.y) << 16);
    v.y = f2bf(a.z) | (f2bf(a.w) << 16);
    v.z = f2bf(b.x) | (f2bf(b.y) << 16);
    v.w = f2bf(b.z) | (f2bf(b.w) << 16);

    size_t off = (size_t)(mt * 64 + kstep) * STRIPE
               + (size_t)r * 128 + (size_t)((s ^ (r & 7)) << 4);
    *reinterpret_cast<uint4*>(dst + off) = v;
}

// ---------------- Pass 2: 256^2 bf16 GEMM, ring-4, reg-prefetch, fast epilogue ----------
// FINAL (r13 consolidation, best measured: GEMM 246.5us / ~1117 TF, MfmaUtil 52%,
// bank conflicts 0, VGPR 124). Structure: BK=32, 512 threads (8 waves, 2M x 4N),
// per-wave 128x64 = 8x4 frags of 16x16; ring-4 LDS slots; stage(t+3) during tile t;
// counted vmcnt(4) per tile (never drains in main loop); r3-verified zero-conflict
// read layout; cross-tile reg-prefetch (pa/pb of t+1 mid-tile, ka of t+1 at tile end);
// setprio(1) around MFMA clusters; fast exp2 tanh-GELU epilogue (+11% over libm).

__global__ __launch_bounds__(512, 2) void gemm_bf16_256(
    const unsigned char* __restrict__ wsA,
    const unsigned char* __restrict__ wsB,
    const float* __restrict__ bias,
    float* __restrict__ out)
{
    __shared__ unsigned char lds[131072];   // [0,64K) = A slots, [64K,128K) = B slots

    // XCD-chunked bijective swizzle
    int id = blockIdx.x;
    int wg = (id & 7) * 64 + (id >> 3);
    int MT = wg & 7;        // 0..7
    int NT = wg >> 3;       // 0..63

    const int tid  = threadIdx.x;
    const int lane = tid & 63;
    const int w    = tid >> 6;
    const int wm   = w >> 2;     // 0..1
    const int wn   = w & 3;      // 0..3
    const int fr   = lane & 15;  // fragment row
    const int fg   = lane >> 4;  // K-quarter 0..3

    const unsigned char* gA = wsA + (size_t)(2 * MT) * TSTRIDE;
    const unsigned char* gB = wsB + (size_t)(2 * NT) * TSTRIDE;

    // ds_read byte addresses (round-3 formulas, zero-conflict verified)
    int addrA[8];
    #pragma unroll
    for (int mi = 0; mi < 8; ++mi) {
        int row = wm * 128 + mi * 16 + fr;
        int L = row >> 1;
        addrA[mi] = L * 128 + (((((row & 1) << 2) | fg) ^ (L & 7)) << 4);
    }
    int addrB[4];
    #pragma unroll
    for (int ni = 0; ni < 4; ++ni) {
        int row = wn * 64 + ni * 16 + fr;
        int L = row >> 1;
        addrB[ni] = L * 128 + (((((row & 1) << 2) | fg) ^ (L & 7)) << 4);
    }

    // staging source offsets (round-3 version, matches the read layout above)
    int offST[2][2];
    #pragma unroll
    for (int j = 0; j < 2; ++j) {
        int c = w * 2 + j;
        int L = c * 8 + (lane >> 3);
        int p = lane & 7;
        int sl = p ^ (L & 7);
        int h = sl >> 2, fgs = sl & 3;
        int row = 2 * L + h;
        #pragma unroll
        for (int kb = 0; kb < 2; ++kb)
            offST[j][kb] = (row >> 7) * TSTRIDE + (row & 127) * 128
                         + ((((kb << 2) | fgs) ^ (row & 7)) << 4);
    }

#define GLDS(SRC, DOFF) __builtin_amdgcn_global_load_lds(                          \
        (const __attribute__((address_space(1))) unsigned int*)(SRC),              \
        (__attribute__((address_space(3))) unsigned int*)(&lds[DOFF]), 16, 0, 0)

#define STAGE_A(KSOFF, KB, SLOT) do {                                              \
        GLDS(gA + (KSOFF) + offST[0][KB], ((SLOT) << 14) + (w * 2 + 0) * 1024);    \
        GLDS(gA + (KSOFF) + offST[1][KB], ((SLOT) << 14) + (w * 2 + 1) * 1024);    \
    } while (0)
#define STAGE_B(KSOFF, KB, SLOT) do {                                              \
        GLDS(gB + (KSOFF) + offST[0][KB], 65536 + ((SLOT) << 14) + (w * 2 + 0) * 1024); \
        GLDS(gB + (KSOFF) + offST[1][KB], 65536 + ((SLOT) << 14) + (w * 2 + 1) * 1024); \
    } while (0)

// prefetch a tile's B[0..3] + A[0..3] fragments into named register arrays
#define READ_PF(PA, PB, SLOT) do {                                                 \
        const unsigned char* La_ = lds + ((SLOT) << 14);                           \
        const unsigned char* Lb_ = lds + 65536 + ((SLOT) << 14);                   \
        _Pragma("unroll") for (int ni = 0; ni < 4; ++ni)                           \
            PB[ni] = *reinterpret_cast<const bf16x8*>(Lb_ + addrB[ni]);            \
        _Pragma("unroll") for (int mi = 0; mi < 4; ++mi)                           \
            PA[mi] = *reinterpret_cast<const bf16x8*>(La_ + addrA[mi]);            \
    } while (0)

// read a tile's A[4..7] fragments into the (single-buffered) ka array
#define READ_KA(SLOT) do {                                                         \
        const unsigned char* Lk_ = lds + ((SLOT) << 14);                           \
        _Pragma("unroll") for (int mi = 0; mi < 4; ++mi)                           \
            ka[mi] = *reinterpret_cast<const bf16x8*>(Lk_ + addrA[4 + mi]);        \
    } while (0)

    f32x4 acc[8][4];
    #pragma unroll
    for (int mi = 0; mi < 8; ++mi)
        #pragma unroll
        for (int ni = 0; ni < 4; ++ni)
            acc[mi][ni] = (f32x4){0.f, 0.f, 0.f, 0.f};

    bf16x8 pa0[4], pb0[4], pa1[4], pb1[4];   // double-buffered prefetch fragments
    bf16x8 ka[4];                            // single-buffered A[4..7] (read 1 tile early)

    // prologue: stage tiles 0,1,2 into slots 0,1,2; wait tiles 0+1 (vmcnt(4)).
    STAGE_A(0, 0, 0);        STAGE_B(0, 0, 0);
    STAGE_A(0, 1, 1);        STAGE_B(0, 1, 1);
    STAGE_A(STRIPE, 0, 2);   STAGE_B(STRIPE, 0, 2);
    asm volatile("s_waitcnt vmcnt(4)" ::: "memory");
    __builtin_amdgcn_sched_barrier(0);
    __builtin_amdgcn_s_barrier();
    __builtin_amdgcn_sched_barrier(0);
    READ_PF(pa0, pb0, 0);
    READ_KA(0);

// one K-tile: both MFMA clusters fire from registers (pa/pb prefetched last tile,
// ka read at end of last tile); next tile's pa/pb read between clusters, its ka read
// after cluster 2; stage tile t+3; counted vmcnt (VMN<0 = last tile, no boundary).
#define TILE_BODY(RSLOT, NSLOT, PA, PB, NPA, NPB, DO_STG, STKS, STKB, SSLOT, DO_PF, VMN) do { \
        if (DO_STG) STAGE_A(STKS, STKB, SSLOT);                                    \
        __builtin_amdgcn_s_setprio(1);                                             \
        _Pragma("unroll") for (int mi = 0; mi < 4; ++mi)                           \
            _Pragma("unroll") for (int ni = 0; ni < 4; ++ni)                       \
                acc[mi][ni] = __builtin_amdgcn_mfma_f32_16x16x32_bf16(             \
                    PA[mi], PB[ni], acc[mi][ni], 0, 0, 0);                         \
        __builtin_amdgcn_s_setprio(0);                                             \
        if (DO_STG) STAGE_B(STKS, STKB, SSLOT);                                    \
        if (DO_PF) READ_PF(NPA, NPB, NSLOT);                                       \
        __builtin_amdgcn_s_setprio(1);                                             \
        _Pragma("unroll") for (int mi = 0; mi < 4; ++mi)                           \
            _Pragma("unroll") for (int ni = 0; ni < 4; ++ni)                       \
                acc[4 + mi][ni] = __builtin_amdgcn_mfma_f32_16x16x32_bf16(         \
                    ka[mi], PB[ni], acc[4 + mi][ni], 0, 0, 0);                     \
        __builtin_amdgcn_s_setprio(0);                                             \
        if (DO_PF) READ_KA(NSLOT);                                                 \
        if ((VMN) >= 0) {                                                          \
            if ((VMN) == 4)      asm volatile("s_waitcnt vmcnt(4)" ::: "memory");  \
            else                 asm volatile("s_waitcnt vmcnt(0)" ::: "memory");  \
            __builtin_amdgcn_sched_barrier(0);                                     \
            __builtin_amdgcn_s_barrier();                                          \
            __builtin_amdgcn_sched_barrier(0);                                     \
        }                                                                          \
    } while (0)

    // main loop: tiles t = 2tp, 2tp+1 for tp = 0..61; stage tile t+3; vmcnt(4) cadence.
    for (int tp = 0; tp < 62; ++tp) {
        const int scur = (tp & 1) << 1;              // slot of tile 2tp (0 or 2)
        const int ks1 = (tp + 1) * STRIPE;           // stage tile 2tp+3 (kb=1)
        const int ks2 = (tp + 2) * STRIPE;           // stage tile 2tp+4 (kb=0)
        TILE_BODY(scur,     scur ^ 1, pa0, pb0, pa1, pb1, 1, ks1, 1, scur ^ 3, 1, 4);
        TILE_BODY(scur ^ 1, scur ^ 2, pa1, pb1, pa0, pb0, 1, ks2, 0, scur,     1, 4);
    }
    // tail: tiles 124..127 in slots 0..3; stage only 127; drain 4 -> 0 -> 0.
    TILE_BODY(0, 1, pa0, pb0, pa1, pb1, 1, 63 * STRIPE, 1, 3, 1, 4);
    TILE_BODY(1, 2, pa1, pb1, pa0, pb0, 0, 0, 0, 0, 1, 0);
    TILE_BODY(2, 3, pa0, pb0, pa1, pb1, 0, 0, 0, 0, 1, 0);
    TILE_BODY(3, 0, pa1, pb1, pa0, pb0, 0, 0, 0, 0, 0, -1);

    // epilogue: bias + fast tanh-GELU, f32 stores (16x16 C/D layout: col=lane&15,
    // row = (lane>>4)*4 + reg).
    const int bm0 = MT * 256, bn0 = NT * 256;
    #pragma unroll
    for (int mi = 0; mi < 8; ++mi) {
        int row = bm0 + wm * 128 + mi * 16 + fg * 4;
        #pragma unroll
        for (int ni = 0; ni < 4; ++ni) {
            int col = bn0 + wn * 64 + ni * 16 + fr;
            float bv = bias[col];
            float* op = out + (size_t)row * N_DIM + col;
            #pragma unroll
            for (int q = 0; q < 4; ++q) {
                float v = acc[mi][ni][q] + bv;
                op[(size_t)q * N_DIM] = gelu_tanh(v);
            }
        }
    }
#undef TILE_BODY
#undef READ_KA
#undef READ_PF
#undef STAGE_A
#undef STAGE_B
#undef GLDS
}

// ---------------- Fallback: round-1 fused kernel (used only if ws too small) ------------
__global__ __launch_bounds__(256, 2) void nvfp4_gemm(
    const float* __restrict__ x,
    const int*   __restrict__ wp,
    const float* __restrict__ wscale,
    const float* __restrict__ bias,
    float* __restrict__ out)
{
    __shared__ uint4  lsA[128 * 8];
    __shared__ uint4  lsB[128 * 8];
    __shared__ float2 lut[256];

    const int tid = threadIdx.x;
    {
        static const float dectab[16] = {0.f, 0.5f, 1.f, 1.5f, 2.f, 3.f, 4.f, 6.f,
                                         -0.f,-0.5f,-1.f,-1.5f,-2.f,-3.f,-4.f,-6.f};
        lut[tid] = make_float2(dectab[tid & 15], dectab[(tid >> 4) & 15]);
    }

    const int bn0 = blockIdx.x * 128;
    const int bm0 = blockIdx.y * 128;
    const int r = tid >> 1;
    const int h = tid & 1;

    const float4* xp = reinterpret_cast<const float4*>(x + (size_t)(bm0 + r) * K_DIM) + h * 8;
    const uint4*  bp = reinterpret_cast<const uint4*>(wp + (size_t)(bn0 + r) * (K_DIM / 2)) + h * 4;
    const float*  sp = wscale + (size_t)(bn0 + r) * (K_DIM / 32) + h;

    float4 ax[8];
    uint4  bx[4];
    float  scale;
    #pragma unroll
    for (int j = 0; j < 8; ++j) ax[j] = xp[j];
    #pragma unroll
    for (int q = 0; q < 4; ++q) bx[q] = bp[q];
    scale = sp[0];

    f32x4 acc[4][4];
    #pragma unroll
    for (int mi = 0; mi < 4; ++mi)
        #pragma unroll
        for (int ni = 0; ni < 4; ++ni)
            acc[mi][ni] = (f32x4){0.f, 0.f, 0.f, 0.f};

    const int lane = tid & 63;
    const int wid  = tid >> 6;
    const int wm0  = (wid >> 1) * 64;
    const int wn0  = (wid & 1) * 64;
    const int fr   = lane & 15;
    const int fg   = lane >> 4;

    __syncthreads();

    for (int kt = 0; kt < 64; ++kt) {
        #pragma unroll
        for (int j = 0; j < 4; ++j) {
            float4 f0 = ax[2 * j], f1 = ax[2 * j + 1];
            uint4 v;
            v.x = f2bf(f0.x) | (f2bf(f0.y) << 16);
            v.y = f2bf(f0.z) | (f2bf(f0.w) << 16);
            v.z = f2bf(f1.x) | (f2bf(f1.y) << 16);
            v.w = f2bf(f1.z) | (f2bf(f1.w) << 16);
            lsA[(r * 8 + h * 4 + j) ^ (r & 7)] = v;
        }
        #pragma unroll
        for (int q = 0; q < 4; ++q) {
            uint4 p = bx[q];
            float2 d0 = lut[p.x & 255];
            float2 d1 = lut[p.y & 255];
            float2 d2 = lut[p.z & 255];
            float2 d3 = lut[p.w & 255];
            uint4 v;
            v.x = f2bf(d0.x * scale) | (f2bf(d0.y * scale) << 16);
            v.y = f2bf(d1.x * scale) | (f2bf(d1.y * scale) << 16);
            v.z = f2bf(d2.x * scale) | (f2bf(d2.y * scale) << 16);
            v.w = f2bf(d3.x * scale) | (f2bf(d3.y * scale) << 16);
            lsB[(r * 8 + h * 4 + q) ^ (r & 7)] = v;
        }
        __syncthreads();

        if (kt + 1 < 64) {
            #pragma unroll
            for (int j = 0; j < 8; ++j) ax[j] = xp[(kt + 1) * 16 + j];
            #pragma unroll
            for (int q = 0; q < 4; ++q) bx[q] = bp[(kt + 1) * 8 + q];
            scale = sp[(kt + 1) * 2];
        }

        #pragma unroll
        for (int kk = 0; kk < 2; ++kk) {
            bf16x8 af[4], bfr[4];
            #pragma unroll
            for (int mi = 0; mi < 4; ++mi) {
                int row = wm0 + mi * 16 + fr;
                af[mi] = __builtin_bit_cast(bf16x8, lsA[(row * 8 + kk * 4 + fg) ^ (row & 7)]);
            }
            #pragma unroll
            for (int ni = 0; ni < 4; ++ni) {
                int row = wn0 + ni * 16 + fr;
                bfr[ni] = __builtin_bit_cast(bf16x8, lsB[(row * 8 + kk * 4 + fg) ^ (row & 7)]);
            }
            #pragma unroll
            for (int mi = 0; mi < 4; ++mi)
                #pragma unroll
                for (int ni = 0; ni < 4; ++ni)
                    acc[mi][ni] = __builtin_amdgcn_mfma_f32_16x16x32_bf16(
                        af[mi], bfr[ni], acc[mi][ni], 0, 0, 0);
        }
        __syncthreads();
    }

    #pragma unroll
    for (int mi = 0; mi < 4; ++mi) {
        int row = bm0 + wm0 + mi * 16 + fg * 4;
        #pragma unroll
        for (int ni = 0; ni < 4; ++ni) {
            int col = bn0 + wn0 + ni * 16 + fr;
            float bv = bias[col];
            float* op = out + (size_t)row * N_DIM + col;
            #pragma unroll
            for (int q = 0; q < 4; ++q) {
                float v = acc[mi][ni][q] + bv;
                op[(size_t)q * N_DIM] = gelu_tanh(v);
            }
        }
    }
}

extern "C" void kernel_launch(void* const* d_in, const int* in_sizes, int n_in,
                              void* d_out, int out_size, void* d_ws, size_t ws_size,
                              hipStream_t stream) {
    const float* x    = (const float*)d_in[0];
    const int*   wp   = (const int*)d_in[1];
    const float* wsc  = (const float*)d_in[2];
    const float* bias = (const float*)d_in[3];
    float*       out  = (float*)d_out;
    (void)in_sizes; (void)n_in; (void)out_size;

    if (ws_size >= WSB_BYTES + WSA_BYTES) {
        unsigned char* wsB = (unsigned char*)d_ws;
        unsigned char* wsA = wsB + WSB_BYTES;
        dequant_w<<<(N_DIM * (K_DIM / 8)) / 256, 256, 0, stream>>>(wp, wsc, wsB);
        conv_x<<<(M_DIM * (K_DIM / 8)) / 256, 256, 0, stream>>>(x, wsA);
        gemm_bf16_256<<<(M_DIM / 256) * (N_DIM / 256), 512, 0, stream>>>(wsA, wsB, bias, out);
    } else {
        dim3 grid(N_DIM / 128, M_DIM / 128);
        nvfp4_gemm<<<grid, 256, 0, stream>>>(x, wp, wsc, bias, out);
    }
}